// Round 11
// baseline (314.941 us; speedup 1.0000x reference)
//
#include <hip/hip_runtime.h>

#define NGRAPHS 64
#define DIM 480            // floats per row
#define NCH 224            // 128 scalar + 64 vec3 + 32 vec5 channels
#define EPS 1e-5f
#define SLOTS 16           // producer blocks per graph (fused path)
#define PSTR 640           // per-slot partial stride: 480 ssq + 128 sum + pad
#define SPIN_BOUND (1u << 24)
#define TILE 128           // rows per tile (fallback path)

typedef float f32x4 __attribute__((ext_vector_type(4)));

__device__ __forceinline__ int col2ch(int col) {
    if (col < 128) return col;
    if (col < 320) return 128 + (col - 128) / 3;
    return 192 + (col - 320) / 5;
}

// ===================== fused single-read path =====================
// grid = 64*16 = 1024 blocks; __launch_bounds__(256,4) guarantees 4 blocks/CU
// resident => all 1024 co-resident => per-graph 16-block spin is deadlock-free.
// KEY CHANGE vs r8: spin polls are RELAXED (no per-poll cache invalidate);
// a single acquire fence after the spin provides the ordering. The r8/r10
// acquire-per-poll emitted an inv op per iteration -> chip-wide TCC storm.
__global__ __launch_bounds__(256, 4) void fused_kernel(
        const float* __restrict__ x, const int* __restrict__ bid,
        const float* __restrict__ w, const float* __restrict__ bias,
        unsigned int* __restrict__ done, float* __restrict__ part,
        float* __restrict__ out, int N) {
    __shared__ int s_se[2];
    __shared__ float red[256][13];          // +1 pad: conflict-free reduce
    __shared__ float lds_col[608];          // per-col ssq[480] + sum[128]

    const int t  = threadIdx.x;
    const int g  = blockIdx.x >> 4;
    const int js = blockIdx.x & (SLOTS - 1);

    // graph bounds via binary search over sorted batch_id
    if (t < 2) {
        int target = g + t, lo = 0, hi = N;
        while (lo < hi) { int mid = (lo + hi) >> 1; if (bid[mid] < target) lo = mid + 1; else hi = mid; }
        s_se[t] = lo;
    }
    __syncthreads();
    const int rs = s_se[0], re = s_se[1];
    const int cnt_i = re - rs;
    const int chunk = (cnt_i + SLOTS - 1) / SLOTS;
    const int r0s = rs + js * chunk;
    const int r1s = min(r0s + chunk, re);

    const int tx = t & 63;
    const int ty = t >> 6;

    // ---- phase 1: slice stats (lane tx owns cols 4tx..+3 and 256+4tx..+3) ----
    float ssq[8]  = {0, 0, 0, 0, 0, 0, 0, 0};
    float ssum[4] = {0, 0, 0, 0};

#define ACC_A(v) { ssq[0] += (v).x*(v).x; ssq[1] += (v).y*(v).y; \
                   ssq[2] += (v).z*(v).z; ssq[3] += (v).w*(v).w; }
#define ACC_S(v) { ssum[0] += (v).x; ssum[1] += (v).y; ssum[2] += (v).z; ssum[3] += (v).w; }
#define ACC_B(v) { ssq[4] += (v).x*(v).x; ssq[5] += (v).y*(v).y; \
                   ssq[6] += (v).z*(v).z; ssq[7] += (v).w*(v).w; }

    int r = r0s + ty;
    for (; r + 4 < r1s; r += 8) {            // wave handles rows r, r+4
        const float4* p0 = (const float4*)(x + (size_t)r * DIM);
        const float4* p1 = (const float4*)(x + (size_t)(r + 4) * DIM);
        float4 a0 = p0[tx], a1 = p1[tx];
        if (tx < 56) {
            float4 b0 = p0[64 + tx], b1 = p1[64 + tx];
            ACC_B(b0); ACC_B(b1);
        }
        ACC_A(a0); ACC_A(a1);
        if (tx < 32) { ACC_S(a0); ACC_S(a1); }
    }
    for (; r < r1s; r += 4) {                // remainder
        const float4* p0 = (const float4*)(x + (size_t)r * DIM);
        float4 a0 = p0[tx];
        if (tx < 56) { float4 b0 = p0[64 + tx]; ACC_B(b0); }
        ACC_A(a0);
        if (tx < 32) ACC_S(a0);
    }

#pragma unroll
    for (int j = 0; j < 8; ++j) red[t][j] = ssq[j];
#pragma unroll
    for (int j = 0; j < 4; ++j) red[t][8 + j] = ssum[j];
    __syncthreads();
    if (ty == 0) {
        float* P = part + (size_t)blockIdx.x * PSTR;   // single writer per slot
#pragma unroll
        for (int j = 0; j < 8; ++j) ssq[j] = red[tx][j] + red[tx + 64][j] + red[tx + 128][j] + red[tx + 192][j];
#pragma unroll
        for (int j = 0; j < 4; ++j) ssum[j] = red[tx][8 + j] + red[tx + 64][8 + j] + red[tx + 128][8 + j] + red[tx + 192][8 + j];
#pragma unroll
        for (int j = 0; j < 4; ++j)
            __hip_atomic_store(&P[4 * tx + j], ssq[j], __ATOMIC_RELAXED, __HIP_MEMORY_SCOPE_AGENT);
        if (tx < 56) {
#pragma unroll
            for (int j = 0; j < 4; ++j)
                __hip_atomic_store(&P[256 + 4 * tx + j], ssq[4 + j], __ATOMIC_RELAXED, __HIP_MEMORY_SCOPE_AGENT);
        }
        if (tx < 32) {
#pragma unroll
            for (int j = 0; j < 4; ++j)
                __hip_atomic_store(&P[480 + 4 * tx + j], ssum[j], __ATOMIC_RELAXED, __HIP_MEMORY_SCOPE_AGENT);
        }
    }
    __syncthreads();                         // all slot stores done (block-wide)

    // ---- publish + spin (per-graph, 16 producers) ----
    if (t == 0) {
        __hip_atomic_fetch_add(&done[g], 1u, __ATOMIC_RELEASE, __HIP_MEMORY_SCOPE_AGENT);
        unsigned it = 0;
        // RELAXED polls: no cache-invalidate per iteration
        while (__hip_atomic_load(&done[g], __ATOMIC_RELAXED, __HIP_MEMORY_SCOPE_AGENT) < SLOTS) {
            if (++it > SPIN_BOUND) break;    // co-residency guaranteed; bound = hang guard
            __builtin_amdgcn_s_sleep(32);
        }
    }
    __syncthreads();
    // single acquire: order the partials-read after the observed releases
    __builtin_amdgcn_fence(__ATOMIC_ACQUIRE, "agent");

    // ---- reduce the 16 slots' per-col partials into LDS ----
    const float* Pg = part + (size_t)g * SLOTS * PSTR;
    for (int col = t; col < 608; col += 256) {
        float a = 0.0f;
        for (int s = 0; s < SLOTS; ++s)
            a += __hip_atomic_load(&Pg[(size_t)s * PSTR + col], __ATOMIC_RELAXED, __HIP_MEMORY_SCOPE_AGENT);
        lds_col[col] = a;
    }
    __syncthreads();

    // ---- phase 2: inline A/B, re-read own slice (cache-hot), nt-store out ----
    if (t < 240) {
        const int row_off = t / 120;         // 0 or 1
        const int c4 = t - row_off * 120;
        float cnt = (float)max(cnt_i, 1);
        float A[4], B[4];
#pragma unroll
        for (int j = 0; j < 4; ++j) {
            int col = 4 * c4 + j;
            if (col < 128) {
                float m   = lds_col[480 + col] / cnt;
                float var = lds_col[col] / cnt - m * m;
                float Av  = rsqrtf(var + EPS) * w[col];
                A[j] = Av;
                B[j] = bias[col] - m * Av;
            } else if (col < 320) {
                int k = (col - 128) / 3, c0 = 128 + 3 * k;
                float sq = lds_col[c0] + lds_col[c0 + 1] + lds_col[c0 + 2];
                A[j] = rsqrtf(sq / (3.0f * cnt) + EPS) * w[128 + k];
                B[j] = 0.0f;
            } else {
                int k = (col - 320) / 5, c0 = 320 + 5 * k;
                float sq = lds_col[c0] + lds_col[c0 + 1] + lds_col[c0 + 2]
                         + lds_col[c0 + 3] + lds_col[c0 + 4];
                A[j] = rsqrtf(sq / (5.0f * cnt) + EPS) * w[192 + k];
                B[j] = 0.0f;
            }
        }
        const int stride4 = 2 * (DIM / 4);   // 2 rows in float4 units
        const int strideF = 2 * DIM;
        int rr = r0s + row_off;
        const float4* xp = (const float4*)(x + (size_t)rr * DIM) + c4;
        float*        op = out + (size_t)rr * DIM + 4 * c4;
        for (; rr + 2 < r1s; rr += 4) {      // 2 rows per iteration
            float4 x0 = xp[0];
            float4 x1 = xp[stride4];
            f32x4 o0, o1;
            o0.x = x0.x * A[0] + B[0]; o0.y = x0.y * A[1] + B[1];
            o0.z = x0.z * A[2] + B[2]; o0.w = x0.w * A[3] + B[3];
            o1.x = x1.x * A[0] + B[0]; o1.y = x1.y * A[1] + B[1];
            o1.z = x1.z * A[2] + B[2]; o1.w = x1.w * A[3] + B[3];
            __builtin_nontemporal_store(o0, (f32x4*)op);
            __builtin_nontemporal_store(o1, (f32x4*)(op + strideF));
            xp += 2 * stride4;
            op += 2 * strideF;
        }
        if (rr < r1s) {
            float4 x0 = xp[0];
            f32x4 o0;
            o0.x = x0.x * A[0] + B[0]; o0.y = x0.y * A[1] + B[1];
            o0.z = x0.z * A[2] + B[2]; o0.w = x0.w * A[3] + B[3];
            __builtin_nontemporal_store(o0, (f32x4*)op);
        }
    }
}

// ===================== fallback: proven r3 3-kernel path (257 us) =====================
#define OFF_SSQ   0
#define OFF_SUM   14336
#define OFF_START 22528
#define OFF_TPRE  22593
#define ZN_FLOATS 22528

__global__ __launch_bounds__(256) void init_kernel(const int* __restrict__ bid,
                                                   float* __restrict__ ws, int N) {
    int b = blockIdx.x;
    if (b < 88) {
        int i = b * 256 + threadIdx.x;
        if (i < ZN_FLOATS) ws[i] = 0.0f;
        return;
    }
    int* start = (int*)(ws + OFF_START);
    int* tpre  = (int*)(ws + OFF_TPRE);
    int g = threadIdx.x;
    if (g <= NGRAPHS) {
        int lo = 0, hi = N;
        while (lo < hi) { int mid = (lo + hi) >> 1; if (bid[mid] < g) lo = mid + 1; else hi = mid; }
        start[g] = lo;
    }
    __syncthreads();
    if (threadIdx.x == 0) {
        int acc = 0;
        for (int gg = 0; gg < NGRAPHS; ++gg) {
            tpre[gg] = acc;
            acc += (start[gg + 1] - start[gg] + TILE - 1) / TILE;
        }
        tpre[NGRAPHS] = acc;
    }
}

__device__ __forceinline__ void block_tile(const int* __restrict__ tpre, int b,
                                           int& g, int& tile) {
    int lo = 0, hi = NGRAPHS;
    while (hi - lo > 1) { int mid = (lo + hi) >> 1; if (tpre[mid] <= b) lo = mid; else hi = mid; }
    g = lo;
    tile = b - tpre[lo];
}

__device__ __forceinline__ void flush_quad(float* __restrict__ SQ, int col0,
                                           float v0, float v1, float v2, float v3) {
    float v[4] = {v0, v1, v2, v3};
    int ch0 = col2ch(col0), ch1 = col2ch(col0 + 1),
        ch2 = col2ch(col0 + 2), ch3 = col2ch(col0 + 3);
    float acc = v[0]; int cur = ch0;
    if (ch1 == cur) acc += v[1]; else { atomicAdd(&SQ[cur], acc); cur = ch1; acc = v[1]; }
    if (ch2 == cur) acc += v[2]; else { atomicAdd(&SQ[cur], acc); cur = ch2; acc = v[2]; }
    if (ch3 == cur) acc += v[3]; else { atomicAdd(&SQ[cur], acc); cur = ch3; acc = v[3]; }
    atomicAdd(&SQ[cur], acc);
}

__global__ __launch_bounds__(256) void stats_kernel(const float* __restrict__ x,
                                                    float* __restrict__ ws) {
    __shared__ float red[256][13];
    const int* start = (const int*)(ws + OFF_START);
    const int* tpre  = (const int*)(ws + OFF_TPRE);
    if ((int)blockIdx.x >= tpre[NGRAPHS]) return;
    int g, tile;
    block_tile(tpre, blockIdx.x, g, tile);
    int r0 = start[g] + tile * TILE;
    int r1 = min(r0 + TILE, start[g + 1]);
    const int t = threadIdx.x, tx = t & 63, ty = t >> 6;
    float ssq[8] = {0,0,0,0,0,0,0,0}, ssum[4] = {0,0,0,0};
    for (int r = r0 + ty; r < r1; r += 4) {
        const float4* rowp = (const float4*)(x + (size_t)r * DIM);
        float4 v0 = rowp[tx];
        ssq[0] += v0.x*v0.x; ssq[1] += v0.y*v0.y; ssq[2] += v0.z*v0.z; ssq[3] += v0.w*v0.w;
        if (tx < 32) { ssum[0] += v0.x; ssum[1] += v0.y; ssum[2] += v0.z; ssum[3] += v0.w; }
        if (tx < 56) {
            float4 v1 = rowp[64 + tx];
            ssq[4] += v1.x*v1.x; ssq[5] += v1.y*v1.y; ssq[6] += v1.z*v1.z; ssq[7] += v1.w*v1.w;
        }
    }
#pragma unroll
    for (int j = 0; j < 8; ++j) red[t][j] = ssq[j];
#pragma unroll
    for (int j = 0; j < 4; ++j) red[t][8 + j] = ssum[j];
    __syncthreads();
    if (ty == 0) {
        float s[8], sm[4];
#pragma unroll
        for (int j = 0; j < 8; ++j)
            s[j] = red[tx][j] + red[tx + 64][j] + red[tx + 128][j] + red[tx + 192][j];
#pragma unroll
        for (int j = 0; j < 4; ++j)
            sm[j] = red[tx][8 + j] + red[tx + 64][8 + j] + red[tx + 128][8 + j] + red[tx + 192][8 + j];
        float* SQ = ws + OFF_SSQ + (size_t)g * NCH;
        float* SM = ws + OFF_SUM + (size_t)g * 128;
        flush_quad(SQ, 4 * tx, s[0], s[1], s[2], s[3]);
        if (tx < 32) {
#pragma unroll
            for (int j = 0; j < 4; ++j) atomicAdd(&SM[4 * tx + j], sm[j]);
        }
        if (tx < 56) flush_quad(SQ, 256 + 4 * tx, s[4], s[5], s[6], s[7]);
    }
}

__global__ __launch_bounds__(256) void norm_kernel(const float* __restrict__ x,
                                                   const float* __restrict__ w,
                                                   const float* __restrict__ bias,
                                                   const float* __restrict__ ws,
                                                   float* __restrict__ out) {
    const int* start = (const int*)(ws + OFF_START);
    const int* tpre  = (const int*)(ws + OFF_TPRE);
    int total = tpre[NGRAPHS];
    int b = total - 1 - (int)blockIdx.x;
    if (b < 0) return;
    int t = threadIdx.x;
    if (t >= 240) return;
    int g, tile;
    block_tile(tpre, b, g, tile);
    int r0 = start[g] + tile * TILE;
    int r1 = min(r0 + TILE, start[g + 1]);
    int row_off = t / 120, c4 = t - row_off * 120;
    float cnt = (float)max(start[g + 1] - start[g], 1);
    const float* SQ = ws + OFF_SSQ + (size_t)g * NCH;
    const float* SM = ws + OFF_SUM + (size_t)g * 128;
    float A[4], B[4];
#pragma unroll
    for (int j = 0; j < 4; ++j) {
        int col = 4 * c4 + j;
        int ch = col2ch(col);
        float ssq = SQ[ch];
        if (col < 128) {
            float m = SM[col] / cnt;
            float var = ssq / cnt - m * m;
            float Av = rsqrtf(var + EPS) * w[ch];
            A[j] = Av; B[j] = bias[col] - m * Av;
        } else {
            float d = (col < 320) ? 3.0f : 5.0f;
            A[j] = rsqrtf(ssq / (d * cnt) + EPS) * w[ch];
            B[j] = 0.0f;
        }
    }
    const float4* xp = (const float4*)(x + (size_t)(r0 + row_off) * DIM) + c4;
    float*        op = out + (size_t)(r0 + row_off) * DIM + 4 * c4;
    const int stride4 = 2 * (DIM / 4);
    const int strideF = 2 * DIM;
    for (int r = r0 + row_off; r < r1; r += 2) {
        float4 xv = *xp;
        f32x4 o;
        o.x = xv.x * A[0] + B[0];
        o.y = xv.y * A[1] + B[1];
        o.z = xv.z * A[2] + B[2];
        o.w = xv.w * A[3] + B[3];
        __builtin_nontemporal_store(o, (f32x4*)op);
        xp += stride4;
        op += strideF;
    }
}

extern "C" void kernel_launch(void* const* d_in, const int* in_sizes, int n_in,
                              void* d_out, int out_size, void* d_ws, size_t ws_size,
                              hipStream_t stream) {
    const float* x   = (const float*)d_in[0];
    const int*   bid = (const int*)d_in[1];
    const float* w   = (const float*)d_in[2];
    const float* b   = (const float*)d_in[3];
    float* ws  = (float*)d_ws;
    float* out = (float*)d_out;
    int N = in_sizes[1];

    size_t need = 64 * sizeof(unsigned) + (size_t)NGRAPHS * SLOTS * PSTR * sizeof(float);
    int occ = 0;
    hipOccupancyMaxActiveBlocksPerMultiprocessor(&occ, fused_kernel, 256, 0);

    if (occ >= 4 && ws_size >= need) {
        // fused single-read path, 16 slots, relaxed spin + single acquire fence
        hipMemsetAsync(ws, 0, 64 * sizeof(unsigned), stream);   // done[] counters
        unsigned* done = (unsigned*)ws;
        float* part = ws + 64;
        fused_kernel<<<NGRAPHS * SLOTS, 256, 0, stream>>>(x, bid, w, b, done, part, out, N);
    } else {
        // proven 3-kernel fallback
        int ntiles_ub = (N + TILE - 1) / TILE + NGRAPHS;
        init_kernel<<<89, 256, 0, stream>>>(bid, ws, N);
        stats_kernel<<<ntiles_ub, 256, 0, stream>>>(x, ws);
        norm_kernel<<<ntiles_ub, 256, 0, stream>>>(x, w, b, ws, out);
    }
}

// Round 12
// 258.846 us; speedup vs baseline: 1.2167x; 1.2167x over previous
//
#include <hip/hip_runtime.h>

#define NGRAPHS 64
#define DIM 480            // floats per row
#define NCH 224            // 128 scalar + 64 vec3 + 32 vec5 channels
#define EPS 1e-5f
#define TILE 128           // rows per (graph-aligned) tile

typedef float f32x4 __attribute__((ext_vector_type(4)));

// ws layout (4-byte slots):
// [0, 14336)        sumsq per (g, channel)        64*224 floats
// [14336, 22528)    sum per (g, scalar channel)   64*128 floats
// [22528, 22593)    start offsets                 65 ints
// [22593, 22658)    tile prefix (tpre[64]=total)  65 ints
#define OFF_SSQ   0
#define OFF_SUM   14336
#define OFF_START 22528
#define OFF_TPRE  22593
#define ZN_FLOATS 22528

__device__ __forceinline__ int col2ch(int col) {
    if (col < 128) return col;
    if (col < 320) return 128 + (col - 128) / 3;
    return 192 + (col - 320) / 5;
}

// K0: blocks 0..87 zero the stats accumulators; block 88 computes per-graph
// start offsets (binary search over sorted batch_id) and the tile-prefix table.
__global__ __launch_bounds__(256) void init_kernel(const int* __restrict__ bid,
                                                   float* __restrict__ ws, int N) {
    int b = blockIdx.x;
    if (b < 88) {
        int i = b * 256 + threadIdx.x;
        if (i < ZN_FLOATS) ws[i] = 0.0f;
        return;
    }
    int* start = (int*)(ws + OFF_START);
    int* tpre  = (int*)(ws + OFF_TPRE);
    int g = threadIdx.x;
    if (g <= NGRAPHS) {
        int lo = 0, hi = N;                 // lower_bound: first i with bid[i] >= g
        while (lo < hi) { int mid = (lo + hi) >> 1; if (bid[mid] < g) lo = mid + 1; else hi = mid; }
        start[g] = lo;
    }
    __syncthreads();
    if (threadIdx.x == 0) {
        int acc = 0;
        for (int gg = 0; gg < NGRAPHS; ++gg) {
            tpre[gg] = acc;
            acc += (start[gg + 1] - start[gg] + TILE - 1) / TILE;
        }
        tpre[NGRAPHS] = acc;
    }
}

// map flat tile index b -> (graph, tile-within-graph). Requires b < tpre[64].
__device__ __forceinline__ void block_tile(const int* __restrict__ tpre, int b,
                                           int& g, int& tile) {
    int lo = 0, hi = NGRAPHS;               // largest g with tpre[g] <= b
    while (hi - lo > 1) {
        int mid = (lo + hi) >> 1;
        if (tpre[mid] <= b) lo = mid; else hi = mid;
    }
    g = lo;
    tile = b - tpre[lo];
}

__device__ __forceinline__ void flush_quad(float* __restrict__ SQ, int col0,
                                           float v0, float v1, float v2, float v3) {
    // combine consecutive cols sharing a channel before the atomic
    float v[4] = {v0, v1, v2, v3};
    int ch0 = col2ch(col0), ch1 = col2ch(col0 + 1),
        ch2 = col2ch(col0 + 2), ch3 = col2ch(col0 + 3);
    float acc = v[0]; int cur = ch0;
    if (ch1 == cur) acc += v[1]; else { atomicAdd(&SQ[cur], acc); cur = ch1; acc = v[1]; }
    if (ch2 == cur) acc += v[2]; else { atomicAdd(&SQ[cur], acc); cur = ch2; acc = v[2]; }
    if (ch3 == cur) acc += v[3]; else { atomicAdd(&SQ[cur], acc); cur = ch3; acc = v[3]; }
    atomicAdd(&SQ[cur], acc);
}

// ---- proven r3 tile bodies, shared by the chunked kernels ----

__device__ __forceinline__ void stats_tile_body(const float* __restrict__ x,
                                                float* __restrict__ ws,
                                                const int* __restrict__ start,
                                                const int* __restrict__ tpre,
                                                int b, float (*red)[13]) {
    int g, tile;
    block_tile(tpre, b, g, tile);
    int r0 = start[g] + tile * TILE;
    int r1 = min(r0 + TILE, start[g + 1]);
    const int t = threadIdx.x, tx = t & 63, ty = t >> 6;
    float ssq[8] = {0,0,0,0,0,0,0,0}, ssum[4] = {0,0,0,0};
    for (int r = r0 + ty; r < r1; r += 4) {
        const float4* rowp = (const float4*)(x + (size_t)r * DIM);
        float4 v0 = rowp[tx];
        ssq[0] += v0.x*v0.x; ssq[1] += v0.y*v0.y; ssq[2] += v0.z*v0.z; ssq[3] += v0.w*v0.w;
        if (tx < 32) { ssum[0] += v0.x; ssum[1] += v0.y; ssum[2] += v0.z; ssum[3] += v0.w; }
        if (tx < 56) {
            float4 v1 = rowp[64 + tx];
            ssq[4] += v1.x*v1.x; ssq[5] += v1.y*v1.y; ssq[6] += v1.z*v1.z; ssq[7] += v1.w*v1.w;
        }
    }
#pragma unroll
    for (int j = 0; j < 8; ++j) red[t][j] = ssq[j];
#pragma unroll
    for (int j = 0; j < 4; ++j) red[t][8 + j] = ssum[j];
    __syncthreads();
    if (ty == 0) {
        float s[8], sm[4];
#pragma unroll
        for (int j = 0; j < 8; ++j)
            s[j] = red[tx][j] + red[tx + 64][j] + red[tx + 128][j] + red[tx + 192][j];
#pragma unroll
        for (int j = 0; j < 4; ++j)
            sm[j] = red[tx][8 + j] + red[tx + 64][8 + j] + red[tx + 128][8 + j] + red[tx + 192][8 + j];
        float* SQ = ws + OFF_SSQ + (size_t)g * NCH;
        float* SM = ws + OFF_SUM + (size_t)g * 128;
        flush_quad(SQ, 4 * tx, s[0], s[1], s[2], s[3]);
        if (tx < 32) {
#pragma unroll
            for (int j = 0; j < 4; ++j) atomicAdd(&SM[4 * tx + j], sm[j]);
        }
        if (tx < 56) flush_quad(SQ, 256 + 4 * tx, s[4], s[5], s[6], s[7]);
    }
}

__device__ __forceinline__ void norm_tile_body(const float* __restrict__ x,
                                               const float* __restrict__ w,
                                               const float* __restrict__ bias,
                                               const float* __restrict__ ws,
                                               float* __restrict__ out,
                                               const int* __restrict__ start,
                                               const int* __restrict__ tpre, int b) {
    int t = threadIdx.x;
    if (t >= 240) return;
    int g, tile;
    block_tile(tpre, b, g, tile);
    int r0 = start[g] + tile * TILE;
    int r1 = min(r0 + TILE, start[g + 1]);
    int row_off = t / 120, c4 = t - row_off * 120;
    float cnt = (float)max(start[g + 1] - start[g], 1);
    const float* SQ = ws + OFF_SSQ + (size_t)g * NCH;
    const float* SM = ws + OFF_SUM + (size_t)g * 128;
    float A[4], B[4];
#pragma unroll
    for (int j = 0; j < 4; ++j) {
        int col = 4 * c4 + j;
        int ch = col2ch(col);
        float ssq = SQ[ch];
        if (col < 128) {
            float m = SM[col] / cnt;
            float var = ssq / cnt - m * m;
            float Av = rsqrtf(var + EPS) * w[ch];
            A[j] = Av; B[j] = bias[col] - m * Av;
        } else {
            float d = (col < 320) ? 3.0f : 5.0f;
            A[j] = rsqrtf(ssq / (d * cnt) + EPS) * w[ch];
            B[j] = 0.0f;
        }
    }
    const float4* xp = (const float4*)(x + (size_t)(r0 + row_off) * DIM) + c4;
    float*        op = out + (size_t)(r0 + row_off) * DIM + 4 * c4;
    const int stride4 = 2 * (DIM / 4);
    const int strideF = 2 * DIM;
    for (int r = r0 + row_off; r < r1; r += 2) {
        float4 xv = *xp;
        f32x4 o;
        o.x = xv.x * A[0] + B[0];
        o.y = xv.y * A[1] + B[1];
        o.z = xv.z * A[2] + B[2];
        o.w = xv.w * A[3] + B[3];
        __builtin_nontemporal_store(o, (f32x4*)op);   // nt: don't evict L3-hot x (r7)
        xp += stride4;
        op += strideF;
    }
}

// D1: stats for half-0 tiles [0, tpre[32])  (~192 MB read, fits L3)
__global__ __launch_bounds__(256) void stats_lo_kernel(const float* __restrict__ x,
                                                       float* __restrict__ ws) {
    __shared__ float red[256][13];
    const int* start = (const int*)(ws + OFF_START);
    const int* tpre  = (const int*)(ws + OFF_TPRE);
    int b = blockIdx.x;
    if (b >= tpre[32]) return;
    stats_tile_body(x, ws, start, tpre, b, red);
}

// D2: ONE dispatch = norm(half0, reversed, L3-hot) + stats(half1).
// norm blocks get low blockIdx -> launch first, read half0 before half1's
// stream churns L3. No intra-dispatch dependency (disjoint graphs/ws rows).
__global__ __launch_bounds__(256) void mixed_kernel(const float* __restrict__ x,
                                                    const float* __restrict__ w,
                                                    const float* __restrict__ bias,
                                                    float* __restrict__ ws,
                                                    float* __restrict__ out) {
    __shared__ float red[256][13];
    const int* start = (const int*)(ws + OFF_START);
    const int* tpre  = (const int*)(ws + OFF_TPRE);
    int T0 = tpre[32], T1 = tpre[NGRAPHS];
    int bb = blockIdx.x;
    if (bb < T0) {
        norm_tile_body(x, w, bias, ws, out, start, tpre, T0 - 1 - bb);
    } else if (bb < T1) {
        stats_tile_body(x, ws, start, tpre, bb, red);
    }
}

// D3: norm(half1, reversed) — reads D2's L3-resident half-1 chunk.
__global__ __launch_bounds__(256) void norm_hi_kernel(const float* __restrict__ x,
                                                      const float* __restrict__ w,
                                                      const float* __restrict__ bias,
                                                      const float* __restrict__ ws,
                                                      float* __restrict__ out) {
    const int* start = (const int*)(ws + OFF_START);
    const int* tpre  = (const int*)(ws + OFF_TPRE);
    int T0 = tpre[32], T1 = tpre[NGRAPHS];
    int b = T1 - 1 - (int)blockIdx.x;
    if (b < T0) return;
    norm_tile_body(x, w, bias, ws, out, start, tpre, b);
}

extern "C" void kernel_launch(void* const* d_in, const int* in_sizes, int n_in,
                              void* d_out, int out_size, void* d_ws, size_t ws_size,
                              hipStream_t stream) {
    const float* x   = (const float*)d_in[0];
    const int*   bid = (const int*)d_in[1];
    const float* w   = (const float*)d_in[2];
    const float* b   = (const float*)d_in[3];
    float* ws  = (float*)d_ws;
    float* out = (float*)d_out;
    int N = in_sizes[1];
    int ntiles_ub = (N + TILE - 1) / TILE + NGRAPHS;   // upper bound on tpre[64]

    init_kernel<<<89, 256, 0, stream>>>(bid, ws, N);
    stats_lo_kernel<<<ntiles_ub, 256, 0, stream>>>(x, ws);
    mixed_kernel<<<ntiles_ub, 256, 0, stream>>>(x, w, b, ws, out);
    norm_hi_kernel<<<ntiles_ub, 256, 0, stream>>>(x, w, b, ws, out);
}